// Round 17
// baseline (183.240 us; speedup 1.0000x reference)
//
#include <hip/hip_runtime.h>

#define DF 128
#define AST 136   // padded LDS row stride (bf16 elems)
#define EPB 4096  // edges per block in bucket passes

typedef float f32x4 __attribute__((ext_vector_type(4)));
typedef short bf16x8 __attribute__((ext_vector_type(8)));

__device__ __forceinline__ ushort f2bf(float f) {
  union { float f; uint u; } c; c.f = f;
  uint u = c.u;
  uint r = (u + 0x7fffu + ((u >> 16) & 1u)) >> 16;   // RNE
  return (ushort)r;
}
__device__ __forceinline__ float bf_lo(uint v) { union { uint u; float f; } c; c.u = v << 16; return c.f; }
__device__ __forceinline__ float bf_hi(uint v) { union { uint u; float f; } c; c.u = v & 0xffff0000u; return c.f; }

__device__ __forceinline__ void addv8(float* acc, uint4 v) {
  acc[0] += bf_lo(v.x); acc[1] += bf_hi(v.x);
  acc[2] += bf_lo(v.y); acc[3] += bf_hi(v.y);
  acc[4] += bf_lo(v.z); acc[5] += bf_hi(v.z);
  acc[6] += bf_lo(v.w); acc[7] += bf_hi(v.w);
}

// convert 8 consecutive f32 to a bf16x8 fragment (RNE, matches f2bf path)
__device__ __forceinline__ bf16x8 f32_to_bf16x8(const float* p) {
  float4 a = *(const float4*)p;
  float4 b = *(const float4*)(p + 4);
  union { ushort u[8]; bf16x8 v; } r;
  r.u[0] = f2bf(a.x); r.u[1] = f2bf(a.y); r.u[2] = f2bf(a.z); r.u[3] = f2bf(a.w);
  r.u[4] = f2bf(b.x); r.u[5] = f2bf(b.y); r.u[6] = f2bf(b.z); r.u[7] = f2bf(b.w);
  return r.v;
}

// ---------------- merged prep + bucket histogram ----------------
__global__ void prep_hist_kernel(const int* __restrict__ dst, int* __restrict__ histG,
                                 int E, int nbuck, int nblocks,
                                 const float* __restrict__ W1, ushort* __restrict__ Wt1,
                                 const float* __restrict__ W2, ushort* __restrict__ Wt2,
                                 const float* __restrict__ W3, ushort* __restrict__ W3t,
                                 ushort* __restrict__ zbN, ushort* __restrict__ ybN) {
  __shared__ int lh[512];
  int tid = threadIdx.x;
  if ((int)blockIdx.x < nblocks) {
    int blk = blockIdx.x;
    for (int i = tid; i < nbuck; i += 256) lh[i] = 0;
    __syncthreads();
    int base = blk * EPB + tid * 4;
#pragma unroll
    for (int it = 0; it < EPB / 1024; ++it) {
      int e = base + it * 1024;
      if (e + 3 < E) {
        int4 d4 = *(const int4*)(dst + e);
        atomicAdd(&lh[d4.x >> 8], 1);
        atomicAdd(&lh[d4.y >> 8], 1);
        atomicAdd(&lh[d4.z >> 8], 1);
        atomicAdd(&lh[d4.w >> 8], 1);
      } else {
#pragma unroll
        for (int q = 0; q < 4; ++q) {
          int ee = e + q;
          if (ee < E) atomicAdd(&lh[dst[ee] >> 8], 1);
        }
      }
    }
    __syncthreads();
    for (int i = tid; i < nbuck; i += 256) histG[(size_t)i * nblocks + blk] = lh[i];
    return;
  }
  int j = ((int)blockIdx.x - nblocks) * 256 + tid;
  if (j < DF * DF) {
    int nr = j >> 7, k = j & 127;
    Wt1[j] = f2bf(W1[(size_t)k * DF + nr]);
    return;
  }
  j -= DF * DF;
  if (j < DF * DF) {
    int nr = j >> 7, k = j & 127;
    Wt2[j] = f2bf(W2[(size_t)k * DF + nr]);
    return;
  }
  j -= DF * DF;
  if (j < 16 * DF) {
    int nr = j >> 7, k = j & 127;
    W3t[j] = (nr < 10) ? f2bf(W3[(size_t)k * 10 + nr]) : (ushort)0;
    return;
  }
  j -= 16 * DF;
  if (j < 16) { ((uint4*)zbN)[j] = (uint4){0, 0, 0, 0}; return; }
  j -= 16;
  if (j < 16) { ((uint4*)ybN)[j] = (uint4){0, 0, 0, 0}; }
}

// ---------------- scan over per-(bucket,block) histogram ----------------
__global__ void scan1_kernel(const int* __restrict__ cnt, int* __restrict__ excl,
                             int* __restrict__ bsums, int n) {
  __shared__ int wsum[4];
  int t = threadIdx.x;
  int base = blockIdx.x * 1024 + t * 4;
  int v[4]; int s = 0;
#pragma unroll
  for (int i = 0; i < 4; i++) { int d = (base + i < n) ? cnt[base + i] : 0; v[i] = s; s += d; }
  int lane = t & 63, w = t >> 6;
  int sc = s;
#pragma unroll
  for (int off = 1; off < 64; off <<= 1) { int o = __shfl_up(sc, off); if (lane >= off) sc += o; }
  if (lane == 63) wsum[w] = sc;
  __syncthreads();
  int woff = 0;
  for (int i = 0; i < w; i++) woff += wsum[i];
  int toff = woff + (sc - s);
#pragma unroll
  for (int i = 0; i < 4; i++) if (base + i < n) excl[base + i] = toff + v[i];
  if (t == 255) bsums[blockIdx.x] = woff + sc;
}

// local exclusive scan of bsums[0..nb) into sbs (nb <= 512), 256 threads
__device__ __forceinline__ void scan_bsums_lds(const int* __restrict__ bsums, int nb,
                                               int* sbs, int* wsum) {
  int t = threadIdx.x;
  int v0 = (2 * t < nb) ? bsums[2 * t] : 0;
  int v1 = (2 * t + 1 < nb) ? bsums[2 * t + 1] : 0;
  int s = v0 + v1;
  int lane = t & 63, w = t >> 6;
  int sc = s;
#pragma unroll
  for (int off = 1; off < 64; off <<= 1) { int o = __shfl_up(sc, off); if (lane >= off) sc += o; }
  if (lane == 63) wsum[w] = sc;
  __syncthreads();
  int woff = 0;
  for (int i = 0; i < w; i++) woff += wsum[i];
  int excl = woff + sc - s;
  sbs[2 * t] = excl;
  sbs[2 * t + 1] = excl + v0;
  __syncthreads();
}

// ---------------- role-split: bucket_scatter || gemm_y = f32(x) @ W1 ----------------
__global__ __launch_bounds__(256) void scatter_gemm_kernel(
    const int* __restrict__ src, const int* __restrict__ dst,
    const int* __restrict__ histE, const int* __restrict__ bsums, int nb,
    uint* __restrict__ eb, int E, int nbuck, int nblocks,
    const float* __restrict__ x, const ushort* __restrict__ Wt1,
    ushort* __restrict__ yb, int n, int ntiles) {
  __shared__ __align__(16) ushort Ws[128 * AST];   // gemm role; scatter overlays cursors here
  int tid = threadIdx.x;
  if ((int)blockIdx.x < nblocks) {
    int* lc   = (int*)Ws;         // 512 ints
    int* sbs  = lc + 512;         // 512 ints
    int* wsum = sbs + 512;        // 4 ints
    int blk = blockIdx.x;
    scan_bsums_lds(bsums, nb, sbs, wsum);
    for (int i = tid; i < nbuck; i += 256) {
      int idx = i * nblocks + blk;
      lc[i] = histE[idx] + sbs[idx >> 10];
    }
    __syncthreads();
    int base = blk * EPB + tid * 4;
#pragma unroll
    for (int it = 0; it < EPB / 1024; ++it) {
      int e = base + it * 1024;
      if (e + 3 < E) {
        int4 s4 = *(const int4*)(src + e);
        int4 d4 = *(const int4*)(dst + e);
        int p0 = atomicAdd(&lc[d4.x >> 8], 1);
        eb[p0] = (uint)s4.x | ((uint)(d4.x & 255) << 24);
        int p1 = atomicAdd(&lc[d4.y >> 8], 1);
        eb[p1] = (uint)s4.y | ((uint)(d4.y & 255) << 24);
        int p2 = atomicAdd(&lc[d4.z >> 8], 1);
        eb[p2] = (uint)s4.z | ((uint)(d4.z & 255) << 24);
        int p3 = atomicAdd(&lc[d4.w >> 8], 1);
        eb[p3] = (uint)s4.w | ((uint)(d4.w & 255) << 24);
      } else {
#pragma unroll
        for (int q = 0; q < 4; ++q) {
          int ee = e + q;
          if (ee < E) {
            int d = dst[ee];
            int pos = atomicAdd(&lc[d >> 8], 1);
            eb[pos] = (uint)src[ee] | ((uint)(d & 255) << 24);
          }
        }
      }
    }
    return;
  }
  // gemm role: yb = bf16(x) @ W1, A read as f32 with in-register convert
  for (int i = tid; i < 128 * 16; i += 256) {
    int r = i >> 4, c = i & 15;
    uint4 v = ((const uint4*)(Wt1 + r * DF))[c];
    *(uint4*)&Ws[r * AST + c * 8] = v;
  }
  __syncthreads();

  int lane = tid & 63, w = tid >> 6;
  int wr = (w >> 1) * 32, wc = (w & 1) * 64;
  int r16 = lane & 15, g8 = (lane >> 4) * 8;
  for (int tile = (int)blockIdx.x - nblocks; tile < ntiles; tile += (int)gridDim.x - nblocks) {
    int node0 = tile * 64;
    int ra = node0 + wr + r16;      if (ra >= n) ra = n - 1;
    int rb = node0 + wr + 16 + r16; if (rb >= n) rb = n - 1;
    const float* pa = x + (size_t)ra * DF + g8;
    const float* pb = x + (size_t)rb * DF + g8;

    f32x4 acc[2][4];
#pragma unroll
    for (int i = 0; i < 2; i++)
#pragma unroll
      for (int j = 0; j < 4; j++) acc[i][j] = (f32x4){0.f, 0.f, 0.f, 0.f};

#pragma unroll
    for (int ks = 0; ks < 4; ++ks) {
      bf16x8 a0 = f32_to_bf16x8(pa + ks * 32);
      bf16x8 a1 = f32_to_bf16x8(pb + ks * 32);
      int k0 = ks * 32 + g8;
#pragma unroll
      for (int j = 0; j < 4; j++) {
        bf16x8 b = *(const bf16x8*)&Ws[(wc + j * 16 + r16) * AST + k0];
        acc[0][j] = __builtin_amdgcn_mfma_f32_16x16x32_bf16(a0, b, acc[0][j], 0, 0, 0);
        acc[1][j] = __builtin_amdgcn_mfma_f32_16x16x32_bf16(a1, b, acc[1][j], 0, 0, 0);
      }
    }

#pragma unroll
    for (int mi = 0; mi < 2; mi++) {
#pragma unroll
      for (int j = 0; j < 4; j++) {
        int col = wc + j * 16 + r16;
        int rowb = wr + mi * 16 + (lane >> 4) * 4;
#pragma unroll
        for (int q = 0; q < 4; q++) {
          int node = node0 + rowb + q;
          if (node < n) yb[(size_t)node * DF + col] = f2bf(acc[mi][j][q]);
        }
      }
    }
  }
}

// ---------------- one block per bucket: counting sort, emit rowptr + csr ----------------
__global__ void bucket_sort_kernel(const uint* __restrict__ eb,
                                   const int* __restrict__ histE, const int* __restrict__ bsums,
                                   int nb, int* __restrict__ rowptr, int* __restrict__ csr,
                                   int N, int E, int nbuck, int nblocks) {
  __shared__ int cnt[256];
  __shared__ int cursor[256];
  __shared__ int sbs[512];
  __shared__ int wsum[4];
  int tid = threadIdx.x, b = blockIdx.x;
  scan_bsums_lds(bsums, nb, sbs, wsum);
  int idx = b * nblocks;
  int beg = histE[idx] + sbs[idx >> 10];
  int end = E;
  if (b + 1 < nbuck) { int i2 = (b + 1) * nblocks; end = histE[i2] + sbs[i2 >> 10]; }
  cnt[tid] = 0;
  __syncthreads();
  for (int e = beg + tid; e < end; e += 256)
    atomicAdd(&cnt[eb[e] >> 24], 1);
  __syncthreads();
  int v = cnt[tid];
  int lane = tid & 63, w = tid >> 6;
  int sc = v;
#pragma unroll
  for (int off = 1; off < 64; off <<= 1) { int o = __shfl_up(sc, off); if (lane >= off) sc += o; }
  if (lane == 63) wsum[w] = sc;
  __syncthreads();
  int woff = 0;
  for (int i = 0; i < w; i++) woff += wsum[i];
  int excl = woff + sc - v;
  int node = (b << 8) + tid;
  if (node <= N) rowptr[node] = beg + excl;
  cursor[tid] = beg + excl;
  __syncthreads();
  for (int e = beg + tid; e < end; e += 256) {
    uint vv = eb[e];
    int pos = atomicAdd(&cursor[vv >> 24], 1);
    csr[pos] = (int)(vv & 0x00FFFFFFu);
  }
}

// ---------------- gather-mean core: acc[8] per 16-lane group ----------------
__device__ __forceinline__ void gather_mean(const ushort* __restrict__ src,
                                            const int* __restrict__ rowptr,
                                            const int* __restrict__ csr,
                                            int node, int n, uint c16, float* acc) {
  int beg = rowptr[node], end = rowptr[node + 1];
  const char* xbase = (const char*)src;
#pragma unroll
  for (int i = 0; i < 8; i++) acc[i] = 0.f;
  int deg = end - beg;
  if (deg > 0) {
#pragma unroll 1
    for (int e = beg; e < end; e += 4) {
      int e1 = e + 1, e2 = e + 2, e3 = e + 3;
      uint r0 = (uint)csr[e];
      uint r1 = (e1 < end) ? (uint)csr[e1] : (uint)n;
      uint r2 = (e2 < end) ? (uint)csr[e2] : (uint)n;
      uint r3 = (e3 < end) ? (uint)csr[e3] : (uint)n;
      uint4 v0 = *(const uint4*)(xbase + (r0 * 256u + c16));
      uint4 v1 = *(const uint4*)(xbase + (r1 * 256u + c16));
      uint4 v2 = *(const uint4*)(xbase + (r2 * 256u + c16));
      uint4 v3 = *(const uint4*)(xbase + (r3 * 256u + c16));
      addv8(acc, v0);
      addv8(acc, v1);
      addv8(acc, v2);
      addv8(acc, v3);
    }
    float inv = 1.0f / (float)deg;
#pragma unroll
    for (int i = 0; i < 8; i++) acc[i] *= inv;
  } else {
    uint4 v = *(const uint4*)(xbase + ((uint)node * 256u + c16));
    float t[8] = {0, 0, 0, 0, 0, 0, 0, 0};
    addv8(t, v);
#pragma unroll
    for (int i = 0; i < 8; i++) acc[i] = t[i];
  }
}

// ---------------- agg1 + fused GEMM2: zb = tanh(mean_or_self(yb)+b1) @ W2 ----------
// Block = 16 nodes. Groups gather+tanh into Hs (bf16); all 4 waves MFMA
// Hs @ Wt2 (B-frags from global, L1-resident); Z stored DIRECTLY from
// C-fragments (16 lanes/row-group cover 32B contiguous) -- 1 sync total.
__global__ __launch_bounds__(256) void agg1_gemm_kernel(
    const ushort* __restrict__ yb, const int* __restrict__ rowptr,
    const int* __restrict__ csr, const float* __restrict__ b1,
    const ushort* __restrict__ Wt2, ushort* __restrict__ zb, int n) {
  __shared__ __align__(16) ushort Hs[16 * AST];
  int tid = threadIdx.x;
  int node = (blockIdx.x * 256 + tid) >> 4;
  int node_ib = tid >> 4;
  uint c16 = (uint)(tid & 15) * 16u;
  uint4 hr = (uint4){0, 0, 0, 0};
  if (node < n) {
    float acc[8];
    gather_mean(yb, rowptr, csr, node, n, c16, acc);
    int d8 = (tid & 15) * 8;
    float4 bA = *(const float4*)(b1 + d8);
    float4 bB = *(const float4*)(b1 + d8 + 4);
    float h0 = tanhf(acc[0] + bA.x), h1 = tanhf(acc[1] + bA.y);
    float h2 = tanhf(acc[2] + bA.z), h3 = tanhf(acc[3] + bA.w);
    float h4 = tanhf(acc[4] + bB.x), h5 = tanhf(acc[5] + bB.y);
    float h6 = tanhf(acc[6] + bB.z), h7 = tanhf(acc[7] + bB.w);
    hr.x = (uint)f2bf(h0) | ((uint)f2bf(h1) << 16);
    hr.y = (uint)f2bf(h2) | ((uint)f2bf(h3) << 16);
    hr.z = (uint)f2bf(h4) | ((uint)f2bf(h5) << 16);
    hr.w = (uint)f2bf(h6) | ((uint)f2bf(h7) << 16);
  }
  *(uint4*)&Hs[node_ib * AST + (tid & 15) * 8] = hr;
  __syncthreads();

  // GEMM: Z[16][128] = Hs @ Wt2^T. Wave w -> cols [w*32, w*32+32).
  int lane = tid & 63, w = tid >> 6;
  int r16 = lane & 15, g8 = (lane >> 4) * 8;
  int wc = w * 32;
  f32x4 zacc[2];
  zacc[0] = (f32x4){0.f, 0.f, 0.f, 0.f};
  zacc[1] = (f32x4){0.f, 0.f, 0.f, 0.f};
#pragma unroll
  for (int ks = 0; ks < 4; ++ks) {
    bf16x8 a = *(const bf16x8*)&Hs[r16 * AST + ks * 32 + g8];
    int k0 = ks * 32 + g8;
#pragma unroll
    for (int j = 0; j < 2; ++j) {
      bf16x8 b = *(const bf16x8*)&Wt2[(size_t)(wc + j * 16 + r16) * DF + k0];
      zacc[j] = __builtin_amdgcn_mfma_f32_16x16x32_bf16(a, b, zacc[j], 0, 0, 0);
    }
  }

  // direct C-fragment store: row = (lane>>4)*4+q, col = wc + j*16 + r16
  int node0 = blockIdx.x * 16;
#pragma unroll
  for (int j = 0; j < 2; ++j) {
    int col = wc + j * 16 + r16;
#pragma unroll
    for (int q = 0; q < 4; ++q) {
      int row = (lane >> 4) * 4 + q;
      int nd = node0 + row;
      if (nd < n) zb[(size_t)nd * DF + col] = f2bf(zacc[j][q]);
    }
  }
}

// ---------------- agg2 + MFMA head: logits = tanh(mean_or_self(zb)+b2) @ W3 + b3 ----------
__global__ __launch_bounds__(256) void agg_head_kernel(
    const ushort* __restrict__ zb, const int* __restrict__ rowptr,
    const int* __restrict__ csr, const float* __restrict__ b2,
    const ushort* __restrict__ W3t, const float* __restrict__ b3,
    float* __restrict__ out, int n) {
  __shared__ __align__(16) ushort Hs[16 * AST];
  __shared__ __align__(16) ushort W3s[16 * AST];
  int tid = threadIdx.x;
  {
    int r = tid >> 4, c = tid & 15;
    uint4 v = ((const uint4*)(W3t + r * DF))[c];
    *(uint4*)&W3s[r * AST + c * 8] = v;
  }
  int node = (blockIdx.x * 256 + tid) >> 4;
  int node_ib = tid >> 4;
  uint c16 = (uint)(tid & 15) * 16u;
  uint4 hr = (uint4){0, 0, 0, 0};
  if (node < n) {
    float acc[8];
    gather_mean(zb, rowptr, csr, node, n, c16, acc);
    int d8 = (tid & 15) * 8;
    float4 bA = *(const float4*)(b2 + d8);
    float4 bB = *(const float4*)(b2 + d8 + 4);
    float h0 = tanhf(acc[0] + bA.x), h1 = tanhf(acc[1] + bA.y);
    float h2 = tanhf(acc[2] + bA.z), h3 = tanhf(acc[3] + bA.w);
    float h4 = tanhf(acc[4] + bB.x), h5 = tanhf(acc[5] + bB.y);
    float h6 = tanhf(acc[6] + bB.z), h7 = tanhf(acc[7] + bB.w);
    hr.x = (uint)f2bf(h0) | ((uint)f2bf(h1) << 16);
    hr.y = (uint)f2bf(h2) | ((uint)f2bf(h3) << 16);
    hr.z = (uint)f2bf(h4) | ((uint)f2bf(h5) << 16);
    hr.w = (uint)f2bf(h6) | ((uint)f2bf(h7) << 16);
  }
  *(uint4*)&Hs[node_ib * AST + (tid & 15) * 8] = hr;
  __syncthreads();

  if (tid < 64) {
    int l16 = tid & 15, g8 = (tid >> 4) * 8;
    f32x4 acc = (f32x4){0.f, 0.f, 0.f, 0.f};
#pragma unroll
    for (int ks = 0; ks < 4; ++ks) {
      bf16x8 a = *(const bf16x8*)&Hs[l16 * AST + ks * 32 + g8];
      bf16x8 b = *(const bf16x8*)&W3s[l16 * AST + ks * 32 + g8];
      acc = __builtin_amdgcn_mfma_f32_16x16x32_bf16(a, b, acc, 0, 0, 0);
    }
    if (l16 < 10) {
      float bv = b3[l16];
#pragma unroll
      for (int q = 0; q < 4; ++q) {
        int nib = (tid >> 4) * 4 + q;
        int nd = blockIdx.x * 16 + nib;
        if (nd < n) out[(size_t)nd * 10 + l16] = acc[q] + bv;
      }
    }
  }
}

extern "C" void kernel_launch(void* const* d_in, const int* in_sizes, int n_in,
                              void* d_out, int out_size, void* d_ws, size_t ws_size,
                              hipStream_t stream) {
  const float* x    = (const float*)d_in[0];
  const int*   esrc = (const int*)d_in[1];
  const int*   edst = (const int*)d_in[2];
  const float* W1   = (const float*)d_in[3];
  const float* b1   = (const float*)d_in[4];
  const float* W2   = (const float*)d_in[5];
  const float* b2   = (const float*)d_in[6];
  const float* W3   = (const float*)d_in[7];
  const float* b3   = (const float*)d_in[8];
  float* out = (float*)d_out;

  const int N = in_sizes[0] / DF;   // 100000
  const int E = in_sizes[1];        // 1600000

  const int nbuck   = (N + 255) >> 8;            // 391
  const int nblocks = (E + EPB - 1) / EPB;       // 391
  const int M = nbuck * nblocks;                 // ~153K

  // workspace layout
  char* ws = (char*)d_ws;
  int*  rowptr = (int*)ws;               // N+1
  int*  csr    = rowptr + (N + 1);       // E
  int*  histG  = csr + E;                // M
  int*  histE  = histG + M;              // M
  int*  bsums2 = histE + M;              // 1024
  uint* eb     = (uint*)(bsums2 + 1024); // E
  size_t off = (size_t)((char*)(eb + E) - ws);
  off = (off + 255) & ~(size_t)255;
  ushort* Wt1 = (ushort*)(ws + off);     off += (size_t)DF * DF * 2;
  ushort* Wt2 = (ushort*)(ws + off);     off += (size_t)DF * DF * 2;
  ushort* W3t = (ushort*)(ws + off);     off += (size_t)16 * DF * 2; off = (off + 255) & ~(size_t)255;
  ushort* yb  = (ushort*)(ws + off);     off += (size_t)(N + 1) * DF * 2; off = (off + 255) & ~(size_t)255;
  ushort* zb  = (ushort*)(ws + off);     // N+1 rows (zero row N)

  // merged prep + hist
  int prep_total = 2 * DF * DF + 16 * DF + 32;
  int prep_blocks = (prep_total + 255) / 256;
  prep_hist_kernel<<<nblocks + prep_blocks, 256, 0, stream>>>(
      edst, histG, E, nbuck, nblocks,
      W1, Wt1, W2, Wt2, W3, W3t,
      zb + (size_t)N * DF, yb + (size_t)N * DF);

  int nb_m = (M + 1023) / 1024;
  int ntiles = (N + 63) / 64;

  scan1_kernel<<<nb_m, 256, 0, stream>>>(histG, histE, bsums2, M);

  // bucket_scatter || gemm_y = f32(x) @ W1
  scatter_gemm_kernel<<<nblocks + 512, 256, 0, stream>>>(
      esrc, edst, histE, bsums2, nb_m, eb, E, nbuck, nblocks,
      x, Wt1, yb, N, ntiles);

  bucket_sort_kernel<<<nbuck, 256, 0, stream>>>(eb, histE, bsums2, nb_m, rowptr, csr, N, E, nbuck, nblocks);

  int agg_blocks = (N + 15) / 16;

  // layer 1 + layer 2 GEMM fused: zb = tanh(mean_or_self(yb)+b1) @ W2
  agg1_gemm_kernel<<<agg_blocks, 256, 0, stream>>>(yb, rowptr, csr, b1, Wt2, zb, N);
  // layer 2 aggregate + MFMA head
  agg_head_kernel<<<agg_blocks, 256, 0, stream>>>(zb, rowptr, csr, b2, W3t, b3, out, N);
}